// Round 8
// baseline (681.802 us; speedup 1.0000x reference)
//
#include <hip/hip_runtime.h>

// SSIM loss, fused: (32,3,512,512) fp32, 11x11 avg pools, out = 1 - mean(ssim_map).
//
// R10 = occupancy round: 5 blocks/CU + grid that can fill them; spill reverted.
//  - CH=16, NBUF=32 -> ring 32x64 float4 = 32768 B EXACTLY -> 5 blocks/CU
//    (runtime LDS granularity is 512 B, per R9's 49184->49664 report; wpart is
//    folded into sH to stay at 32768).
//  - Grid = 1536 half-strips (64w x 256h): 768 strips could never exceed
//    3 blocks/CU; 1536 lets 5/CU fill (~17 effective waves after tail).
//  - Staging: 128 threads (16 rows x 8 runs of 8) -> same VERIFIED R8 swizzle:
//    store (xr<<3)+(k^xr), read lx = lane^((lane>>3)&7). Per-row stage-B issue
//    unchanged vs R9.
//  - Stage C: 4 waves x 4 rows/chunk; running-sum old-tap RE-READ from LDS
//    (kills rr[8] = -32 VGPR). Ring wrap = &2047 (power-of-2).
//  - Addressing: R8-style inline recompute (R9's hoisted goff/xm arrays caused
//    ~27 dwords/thread scratch spill -> WRITE_SIZE 21.4 MB + dur regression).
//  - Carried: prefetch-hold across stage C (loads in flight through LDS-only
//    barriers: lgkmcnt + raw s_barrier, no vmcnt drain), sched_barrier(0) pin,
//    rcp+NR division, separate <<<1,1>>> finalize (R5 threadfence lesson).

#define IMGW 512
#define IMGPIX (IMGW * IMGW)
#define CH 16
#define NCHUNK 16          // 256 rows per block / CH
#define NBUF 32            // ring slots (power of 2)
#define RINGF4 (NBUF * 64) // 2048 float4
#define RMASK (RINGF4 - 1)
#define NBLK 1536          // 8 col-strips x 2 halves x 96 images

__global__ __launch_bounds__(256, 5)
void ssim_strip(const float* __restrict__ pred,
                const float* __restrict__ target,
                double* __restrict__ accum)
{
    __shared__ float4 sH[RINGF4];        // 32768 B exactly -> 5 blocks/CU

    const int tid = threadIdx.x;
    const int b = blockIdx.x;
    const int bx = b & 7, hh = (b >> 3) & 1, img = b >> 4;
    const float* __restrict__ p = pred   + (size_t)img * IMGPIX;
    const float* __restrict__ t = target + (size_t)img * IMGPIX;
    const int ybase = hh << 8;           // 0 or 256

    const bool stager = tid < 128;
    const int j2 = tid >> 3;             // staging row 0..15 (stagers)
    const int xr = tid & 7;              // 8-col run
    const int xoff = bx * 64 + xr * 8 - 8;        // leftmost col of 24-col span
    const bool edge = (bx == 0) | (bx == 7);      // block-uniform
    const int lane = tid & 63;
    const int w = tid >> 6;
    const int lx = lane ^ ((lane >> 3) & 7);      // verified read swizzle

    float fp[24], ft[24];

    // load one row's 24-col span [xoff, xoff+24) into regs; zero if row OOB
    auto loadRow = [&](int r) {
        const bool rok = (unsigned)r < (unsigned)IMGW;
        if (rok) {
            const float* pr = p + (size_t)r * IMGW;
            const float* tr = t + (size_t)r * IMGW;
            if (!edge) {
#pragma unroll
                for (int c2 = 0; c2 < 6; ++c2) {
                    const float4 pv = *(const float4*)(pr + xoff + 4 * c2);
                    const float4 tv = *(const float4*)(tr + xoff + 4 * c2);
                    fp[4*c2+0]=pv.x; fp[4*c2+1]=pv.y; fp[4*c2+2]=pv.z; fp[4*c2+3]=pv.w;
                    ft[4*c2+0]=tv.x; ft[4*c2+1]=tv.y; ft[4*c2+2]=tv.z; ft[4*c2+3]=tv.w;
                }
            } else {
#pragma unroll
                for (int c2 = 0; c2 < 6; ++c2) {
                    const int gx = xoff + 4 * c2;
                    const bool ok = (unsigned)gx < (unsigned)IMGW;
                    const int gxc = gx < 0 ? 0 : (gx > IMGW - 4 ? IMGW - 4 : gx);
                    const float4 pv = *(const float4*)(pr + gxc);
                    const float4 tv = *(const float4*)(tr + gxc);
                    const float m = ok ? 1.f : 0.f;
                    fp[4*c2+0]=pv.x*m; fp[4*c2+1]=pv.y*m;
                    fp[4*c2+2]=pv.z*m; fp[4*c2+3]=pv.w*m;
                    ft[4*c2+0]=tv.x*m; ft[4*c2+1]=tv.y*m;
                    ft[4*c2+2]=tv.z*m; ft[4*c2+3]=tv.w*m;
                }
            }
        } else {
#pragma unroll
            for (int i = 0; i < 24; ++i) { fp[i] = 0.f; ft[i] = 0.f; }
        }
    };

    // horizontal 11-sums of 4 planes -> ring at float4-index base sb (=slot<<6)
    auto stageB = [&](int sb) {
        float s1 = 0.f, s2 = 0.f, s3 = 0.f, s4 = 0.f;
#pragma unroll
        for (int i = 3; i <= 13; ++i) {
            s1 += fp[i]; s2 += ft[i];
            s3 += fp[i]*fp[i] + ft[i]*ft[i];
            s4 += fp[i]*ft[i];
        }
        const int wbi = sb + (xr << 3);
#pragma unroll
        for (int k = 0; k < 8; ++k) {
            if (k) {
                const int a = k + 13, bb = k + 2;
                s1 += fp[a] - fp[bb];
                s2 += ft[a] - ft[bb];
                s3 += (fp[a]*fp[a] + ft[a]*ft[a]) - (fp[bb]*fp[bb] + ft[bb]*ft[bb]);
                s4 += fp[a]*ft[a] - fp[bb]*ft[bb];
            }
            sH[wbi + (k ^ xr)] = make_float4(s1, s2, s3, s4);
        }
    };

    // LDS-only barrier: no vmcnt drain (prefetch loads stay in flight)
    auto barrier_lds = [&]() {
        asm volatile("s_waitcnt lgkmcnt(0)" ::: "memory");
        __builtin_amdgcn_s_barrier();
        asm volatile("" ::: "memory");
    };

    // ---- head: local rows lr 0..25 = image rows ybase-5 .. ybase+20 ----
    if (stager) {
        loadRow(ybase - 5 + j2);         // lr j2 (guarded: h=0 head rows <0)
        stageB(j2 << 6);
        if (tid < 80) {                  // lr 16..25, rows ybase+11..+20, valid
            loadRow(ybase + 11 + j2);
            stageB((16 + j2) << 6);
        }
    }
    barrier_lds();

    const float inv = 1.0f / 121.0f;
    const float C1 = 1e-4f, C2 = 9e-4f;

    int cri = (4 * w) << 6;              // stage-C ring base (slot 4w), +1024/chunk
    int sb  = ((26 + j2) & 31) << 6;     // stage-B ring base, +1024/chunk
    double acc = 0.0;

    for (int c = 0; c < NCHUNK; ++c) {
        // issue next stage-B rows (lr 16c+26+j2 = rows ybase+16c+21+j2);
        // in flight through stage C + barrier, consumed at stageB below.
        // c==14,h==1 reaches rows 501..516 -> loadRow zero-guards >511.
        if (stager && c < NCHUNK - 1) loadRow(ybase + 16 * c + 21 + j2);
        __builtin_amdgcn_sched_barrier(0);

        // ---- stage C: vertical 11-sums (lane = col), wave w owns 4 rows ----
        int ri = cri + lx;               // walking read ptr
        int rj = ri;                     // re-read ptr (old taps)
        float4 S = {0.f, 0.f, 0.f, 0.f};
#pragma unroll
        for (int i = 0; i < 10; ++i) {
            const float4 a = sH[ri]; ri = (ri + 64) & RMASK;
            S.x += a.x; S.y += a.y; S.z += a.z; S.w += a.w;
        }
        float tl = 0.f;
#pragma unroll
        for (int k = 0; k < 4; ++k) {
            const float4 nw = sH[ri]; ri = (ri + 64) & RMASK;
            const float W1 = S.x + nw.x, W2 = S.y + nw.y;
            const float W3 = S.z + nw.z, W4 = S.w + nw.w;
            const float4 old = sH[rj]; rj = (rj + 64) & RMASK;
            S.x = W1 - old.x; S.y = W2 - old.y;
            S.z = W3 - old.z; S.w = W4 - old.w;

            const float mu1 = W1 * inv, mu2 = W2 * inv;
            const float E3  = W3 * inv, E12 = W4 * inv;
            const float mu11 = mu1*mu1, mu22 = mu2*mu2, mu12 = mu1*mu2;
            const float num = (2.f*mu12 + C1) * (2.f*(E12 - mu12) + C2);
            const float den = (mu11 + mu22 + C1) * ((E3 - mu11 - mu22) + C2);
            float rdn = __builtin_amdgcn_rcpf(den);
            rdn = rdn * __builtin_fmaf(-den, rdn, 2.0f);   // 1 NR step
            tl += num * rdn;
        }
        acc += (double)tl;
        cri = (cri + CH * 64) & RMASK;

        barrier_lds();                   // stage-C reads done -> slots writable
        if (stager && c < NCHUNK - 1) {
            stageB(sb);                  // vmcnt waits on prefetched regs here
            sb = (sb + CH * 64) & RMASK;
        }
        barrier_lds();                   // writes visible for next stage C
    }

    // ---- block reduce -> one double atomic per block (reuse sH as scratch) ----
#pragma unroll
    for (int off = 32; off > 0; off >>= 1)
        acc += __shfl_down(acc, off, 64);
    __syncthreads();                     // all sH reads complete everywhere
    if (lane == 0) ((double*)sH)[w] = acc;
    __syncthreads();
    if (tid == 0) {
        const double* red = (const double*)sH;
        atomicAdd(accum, red[0] + red[1] + red[2] + red[3]);
    }
}

__global__ void ssim_finalize(const double* __restrict__ accum,
                              float* __restrict__ out) {
    const double n = 25165824.0;  // 32*3*512*512
    out[0] = (float)(1.0 - accum[0] / n);
}

extern "C" void kernel_launch(void* const* d_in, const int* in_sizes, int n_in,
                              void* d_out, int out_size, void* d_ws, size_t ws_size,
                              hipStream_t stream) {
    const float* pred   = (const float*)d_in[0];
    const float* target = (const float*)d_in[1];
    float* out = (float*)d_out;
    double* accum = (double*)d_ws;

    hipMemsetAsync(d_ws, 0, sizeof(double), stream);

    ssim_strip<<<dim3(NBLK), dim3(256), 0, stream>>>(pred, target, accum);
    ssim_finalize<<<1, 1, 0, stream>>>(accum, out);
}